// Round 16
// baseline (361.065 us; speedup 1.0000x reference)
//
#include <hip/hip_runtime.h>

#define IDIM 512
#define MIXD 32
#define HID 96
#define BB 256
#define TT 512
#define TROWS 32
#define SROW 516   // padded LDS row stride (floats)

typedef float f32x2 __attribute__((ext_vector_type(2)));
typedef float f32x4 __attribute__((ext_vector_type(4)));

#define EXP2(x) __builtin_amdgcn_exp2f(x)

template <int CTRL>
__device__ __forceinline__ float dpp_shl_add(float x) {
    int m = __builtin_amdgcn_update_dpp(0, __float_as_int(x), CTRL, 0xf, 0xf, true);
    return x + __int_as_float(m);
}
__device__ __forceinline__ float octet_reduce_lane0(float x) {
    x = dpp_shl_add<0x104>(x);   // row_shl:4
    x = dpp_shl_add<0x102>(x);   // row_shl:2
    x = dpp_shl_add<0x101>(x);   // row_shl:1
    return x;
}
__device__ __forceinline__ float red16(float x) {
    x = dpp_shl_add<0x108>(x);   // row_shl:8
    x = dpp_shl_add<0x104>(x);
    x = dpp_shl_add<0x102>(x);
    x = dpp_shl_add<0x101>(x);
    return x;
}
// k_mix keeps the proven pkfma asm (R15: 84 -> ~55 us); k_scan reverts to
// builtin fma (R15 showed the asm chain HURT the scan: 286 -> 299).
__device__ __forceinline__ f32x2 pkfma(f32x2 a, f32x2 b, f32x2 c) {
    asm("v_pk_fma_f32 %0, %1, %2, %0" : "+v"(c) : "v"(a), "v"(b));
    return c;
}

// ---------------- K1: z = x @ W_mix^T (R15 v7 — unchanged, proven ~55us) ----
__global__ __launch_bounds__(256) void k_mix(const float* __restrict__ x,
                                             const float* __restrict__ Wmix,
                                             float* __restrict__ z) {
    __shared__ __align__(16) float sx[TROWS * SROW];   // 66 KB
    const int tid = threadIdx.x;
    const int mg = (tid >> 4) & 7, ks = tid & 15, rr = tid >> 7;

    f32x2 w[4][16];
    #pragma unroll
    for (int mm = 0; mm < 4; ++mm) {
        #pragma unroll
        for (int i = 0; i < 8; ++i) {
            const int cj = (i + ks) & 7;
            f32x4 v = *(const f32x4*)(Wmix + (size_t)(4 * mg + mm) * IDIM + ks * 32 + cj * 4);
            w[mm][2*i] = v.xy; w[mm][2*i+1] = v.zw;
        }
    }

    const size_t rowbase = (size_t)blockIdx.x * 256;
    const float* xb = x + rowbase * IDIM;

    f32x4 st[16];
    #pragma unroll
    for (int i = 0; i < 16; ++i)
        st[i] = *(const f32x4*)(xb + (size_t)(tid + 256 * i) * 4);

    for (int t = 0; t < 8; ++t) {
        #pragma unroll
        for (int i = 0; i < 16; ++i) {
            const int v = tid + 256 * i, r = v >> 7, c = v & 127;
            *(f32x4*)(&sx[r * SROW + c * 4]) = st[i];
        }
        __syncthreads();

        if (t + 1 < 8) {
            const float* xn = xb + (size_t)(t + 1) * TROWS * IDIM;
            #pragma unroll
            for (int i = 0; i < 16; ++i)
                st[i] = *(const f32x4*)(xn + (size_t)(tid + 256 * i) * 4);
        }

        float* zp = z + (rowbase + (size_t)t * TROWS) * MIXD + 4 * mg;
        for (int rl = 0; rl < 16; ++rl) {
            const int r = rr * 16 + rl;
            const float* rp = sx + r * SROW + ks * 32;
            f32x2 a0 = {0.f,0.f}, a1 = {0.f,0.f}, a2 = {0.f,0.f}, a3 = {0.f,0.f};
            #pragma unroll
            for (int i = 0; i < 8; ++i) {
                f32x4 v = *(const f32x4*)(rp + ((i + ks) & 7) * 4);
                a0 = pkfma(w[0][2*i], v.xy, a0); a0 = pkfma(w[0][2*i+1], v.zw, a0);
                a1 = pkfma(w[1][2*i], v.xy, a1); a1 = pkfma(w[1][2*i+1], v.zw, a1);
                a2 = pkfma(w[2][2*i], v.xy, a2); a2 = pkfma(w[2][2*i+1], v.zw, a2);
                a3 = pkfma(w[3][2*i], v.xy, a3); a3 = pkfma(w[3][2*i+1], v.zw, a3);
            }
            float s0 = red16(a0.x + a0.y);
            float s1 = red16(a1.x + a1.y);
            float s2 = red16(a2.x + a2.y);
            float s3 = red16(a3.x + a3.y);
            if (ks == 0) {
                f32x4 o4 = { s0, s1, s2, s3 };
                *(f32x4*)(zp + (size_t)r * MIXD) = o4;
            }
        }
        __syncthreads();
    }
}

// ---------------- K2: GRU scan + head (R12 body + ih-precompute pipeline) ---
// 256 threads = 4 waves. NEW vs R12: the z-dependent gate partials (pR, pU,
// pXN) for step t+1 are computed at the END of step t, in the barrier-wait
// shadow (z for the whole chunk is already in LDS). The post-barrier critical
// path is then only: h-read -> hh fmas -> DPP reduce -> act -> write.
__global__ __launch_bounds__(256, 1) void k_scan(const float* __restrict__ z,
                                                 const float* __restrict__ Wih,
                                                 const float* __restrict__ Whh,
                                                 const float* __restrict__ bih,
                                                 const float* __restrict__ bhh,
                                                 const float* __restrict__ Whead,
                                                 const float* __restrict__ bhead,
                                                 const float* __restrict__ Wmix,
                                                 float* __restrict__ y) {
    const int b   = blockIdx.x;
    const int tid = threadIdx.x;
    const int j0  = tid >> 3;     // 0..31
    const int o   = tid & 7;      // 0..7
    const float L  = 1.4426950408889634f;   // log2(e)
    const float L2 = 2.8853900817779268f;   // 2*log2(e)

    __shared__ __align__(16) float sz[256 * MIXD];   // 32 KB: half of the z row
    __shared__ __align__(16) float shp[2][HID];      // h ping-pong
    __shared__ __align__(16) float szn[MIXD];

    f32x2 whr[3][6], whu[3][6], whn[3][6], wir[3][2], wiu[3][2], win[3][2];
    float br[3], bu[3], bxn[3], bhn[3];
    #pragma unroll
    for (int i = 0; i < 3; ++i) {
        const int j = j0 + 32 * i;
        #pragma unroll
        for (int c = 0; c < 3; ++c) {
            f32x4 v = *(const f32x4*)(Whh + (size_t)(j        ) * HID + o * 12 + c * 4);
            v *= L;  whr[i][2*c] = v.xy; whr[i][2*c+1] = v.zw;
        }
        #pragma unroll
        for (int c = 0; c < 3; ++c) {
            f32x4 v = *(const f32x4*)(Whh + (size_t)(j +   HID) * HID + o * 12 + c * 4);
            v *= L;  whu[i][2*c] = v.xy; whu[i][2*c+1] = v.zw;
        }
        #pragma unroll
        for (int c = 0; c < 3; ++c) {
            f32x4 v = *(const f32x4*)(Whh + (size_t)(j + 2*HID) * HID + o * 12 + c * 4);
            v *= L2; whn[i][2*c] = v.xy; whn[i][2*c+1] = v.zw;
        }
        {
            f32x4 v = *(const f32x4*)(Wih + (size_t)(j        ) * MIXD + o * 4);
            v *= L;  wir[i][0] = v.xy; wir[i][1] = v.zw;
        }
        {
            f32x4 v = *(const f32x4*)(Wih + (size_t)(j +   HID) * MIXD + o * 4);
            v *= L;  wiu[i][0] = v.xy; wiu[i][1] = v.zw;
        }
        {
            f32x4 v = *(const f32x4*)(Wih + (size_t)(j + 2*HID) * MIXD + o * 4);
            v *= L2; win[i][0] = v.xy; win[i][1] = v.zw;
        }
        br[i]  = (o == 0) ? L  * (bih[j]       + bhh[j])       : 0.f;
        bu[i]  = (o == 0) ? L  * (bih[j + HID] + bhh[j + HID]) : 0.f;
        bxn[i] = (o == 0) ? L2 * bih[j + 2*HID] : 0.f;
        bhn[i] = (o == 0) ? L2 * bhh[j + 2*HID] : 0.f;
    }

    float hown[3] = {0.f, 0.f, 0.f};
    if (tid < HID) shp[0][tid] = 0.f;

    const f32x4* zb4 = (const f32x4*)(z + (size_t)b * TT * MIXD);
    f32x4* sz4 = (f32x4*)sz;

    for (int c = 0; c < TT / 256; ++c) {
        #pragma unroll
        for (int i = 0; i < 8; ++i)
            sz4[tid + 256 * i] = zb4[c * 2048 + tid + 256 * i];
        __syncthreads();

        // preamble: ih partials for tt = 0
        f32x2 pR[3], pU[3], pXN[3];
        {
            const f32x4 z4 = *(const f32x4*)(sz + o * 4);
            #pragma unroll
            for (int i = 0; i < 3; ++i) {
                pR[i]  = {br[i],  0.f};
                pU[i]  = {bu[i],  0.f};
                pXN[i] = {bxn[i], 0.f};
                pR[i]  = __builtin_elementwise_fma(wir[i][0], z4.xy, pR[i]);
                pR[i]  = __builtin_elementwise_fma(wir[i][1], z4.zw, pR[i]);
                pU[i]  = __builtin_elementwise_fma(wiu[i][0], z4.xy, pU[i]);
                pU[i]  = __builtin_elementwise_fma(wiu[i][1], z4.zw, pU[i]);
                pXN[i] = __builtin_elementwise_fma(win[i][0], z4.xy, pXN[i]);
                pXN[i] = __builtin_elementwise_fma(win[i][1], z4.zw, pXN[i]);
            }
        }

        for (int tt = 0; tt < 256; ++tt) {
            const int t = (c << 8) + tt;
            const float* hr = shp[t & 1];
            float*       hw = shp[(t + 1) & 1];

            const f32x4 h0 = *(const f32x4*)(hr + o * 12);
            const f32x4 h1 = *(const f32x4*)(hr + o * 12 + 4);
            const f32x4 h2 = *(const f32x4*)(hr + o * 12 + 8);
            const f32x2 hh[6] = { h0.xy, h0.zw, h1.xy, h1.zw, h2.xy, h2.zw };

            float hv[3];
            #pragma unroll
            for (int i = 0; i < 3; ++i) {
                f32x2 aR  = pR[i];
                f32x2 aU  = pU[i];
                f32x2 aXN = pXN[i];
                f32x2 aHN = {bhn[i], 0.f};

                #pragma unroll
                for (int k = 0; k < 6; ++k) {
                    aR  = __builtin_elementwise_fma(whr[i][k], hh[k], aR);
                    aU  = __builtin_elementwise_fma(whu[i][k], hh[k], aU);
                    aHN = __builtin_elementwise_fma(whn[i][k], hh[k], aHN);
                }

                float sR  = octet_reduce_lane0(aR.x  + aR.y);
                float sU  = octet_reduce_lane0(aU.x  + aU.y);
                float sXN = octet_reduce_lane0(aXN.x + aXN.y);
                float sHN = octet_reduce_lane0(aHN.x + aHN.y);

                float r = __builtin_amdgcn_rcpf(1.f + EXP2(-sR));
                float u = __builtin_amdgcn_rcpf(1.f + EXP2(-sU));
                float n = 1.f - 2.f * __builtin_amdgcn_rcpf(1.f + EXP2(sXN + r * sHN));
                hv[i] = u * (hown[i] - n) + n;   // lane0 correct; others garbage
                hown[i] = hv[i];
            }
            if (o == 0) {
                hw[j0]      = hv[0];
                hw[j0 + 32] = hv[1];
                hw[j0 + 64] = hv[2];
            }

            // barrier-shadow: ih partials for tt+1 (z already in LDS)
            if (tt + 1 < 256) {
                const f32x4 z4n = *(const f32x4*)(sz + (tt + 1) * MIXD + o * 4);
                #pragma unroll
                for (int i = 0; i < 3; ++i) {
                    pR[i]  = {br[i],  0.f};
                    pU[i]  = {bu[i],  0.f};
                    pXN[i] = {bxn[i], 0.f};
                    pR[i]  = __builtin_elementwise_fma(wir[i][0], z4n.xy, pR[i]);
                    pR[i]  = __builtin_elementwise_fma(wir[i][1], z4n.zw, pR[i]);
                    pU[i]  = __builtin_elementwise_fma(wiu[i][0], z4n.xy, pU[i]);
                    pU[i]  = __builtin_elementwise_fma(wiu[i][1], z4n.zw, pU[i]);
                    pXN[i] = __builtin_elementwise_fma(win[i][0], z4n.xy, pXN[i]);
                    pXN[i] = __builtin_elementwise_fma(win[i][1], z4n.zw, pXN[i]);
                }
            }
            __syncthreads();                    // the ONLY barrier per step
        }
    }

    // ---- fused head: zn = Whead @ h + bhead ; y = zn @ Wmix ----
    if (tid < MIXD) {
        const float* h = shp[0];                 // TT even -> final h in shp[0]
        float a0 = 0.f, a1 = 0.f, a2 = 0.f, a3 = 0.f;
        #pragma unroll
        for (int kc = 0; kc < HID / 4; ++kc) {
            f32x4 wv = *(const f32x4*)(Whead + (size_t)tid * HID + kc * 4);
            f32x4 hv4 = *(const f32x4*)(h + kc * 4);
            a0 += wv.x * hv4.x; a1 += wv.y * hv4.y;
            a2 += wv.z * hv4.z; a3 += wv.w * hv4.w;
        }
        szn[tid] = bhead[tid] + ((a0 + a1) + (a2 + a3));
    }
    __syncthreads();
    #pragma unroll
    for (int rep = 0; rep < 2; ++rep) {
        const int col = tid + 256 * rep;
        float acc = 0.f;
        #pragma unroll
        for (int m = 0; m < MIXD; ++m)
            acc += szn[m] * Wmix[(size_t)m * IDIM + col];
        y[(size_t)b * IDIM + col] = acc;
    }
}

extern "C" void kernel_launch(void* const* d_in, const int* in_sizes, int n_in,
                              void* d_out, int out_size, void* d_ws, size_t ws_size,
                              hipStream_t stream) {
    const float* x     = (const float*)d_in[0];
    const float* Wmix  = (const float*)d_in[1];
    const float* Wih   = (const float*)d_in[2];
    const float* Whh   = (const float*)d_in[3];
    const float* bih   = (const float*)d_in[4];
    const float* bhh   = (const float*)d_in[5];
    const float* Whead = (const float*)d_in[6];
    const float* bhead = (const float*)d_in[7];
    float* out = (float*)d_out;

    float* z = (float*)d_ws;   // [B*T, 32] = 16.78 MB

    k_mix <<<512, 256, 0, stream>>>(x, Wmix, z);
    k_scan<<<BB,  256, 0, stream>>>(z, Wih, Whh, bih, bhh, Whead, bhead, Wmix, out);
}

// Round 17
// 328.497 us; speedup vs baseline: 1.0991x; 1.0991x over previous
//
#include <hip/hip_runtime.h>

#define IDIM 512
#define MIXD 32
#define HID 96
#define BB 256
#define TT 512
#define TROWS 32
#define SROW 516   // padded LDS row stride (floats)

typedef float f32x2 __attribute__((ext_vector_type(2)));
typedef float f32x4 __attribute__((ext_vector_type(4)));

#define EXP2(x) __builtin_amdgcn_exp2f(x)

template <int CTRL>
__device__ __forceinline__ float dpp_shl_add(float x) {
    int m = __builtin_amdgcn_update_dpp(0, __float_as_int(x), CTRL, 0xf, 0xf, true);
    return x + __int_as_float(m);
}
__device__ __forceinline__ float octet_reduce_lane0(float x) {
    x = dpp_shl_add<0x104>(x);   // row_shl:4
    x = dpp_shl_add<0x102>(x);   // row_shl:2
    x = dpp_shl_add<0x101>(x);   // row_shl:1
    return x;
}
__device__ __forceinline__ float red16(float x) {
    x = dpp_shl_add<0x108>(x);   // row_shl:8
    x = dpp_shl_add<0x104>(x);
    x = dpp_shl_add<0x102>(x);
    x = dpp_shl_add<0x101>(x);
    return x;
}
// pkfma asm: proven WIN in k_mix (84 -> ~55 us), proven LOSS in k_scan
// (286 -> 299) — used only in k_mix.
__device__ __forceinline__ f32x2 pkfma(f32x2 a, f32x2 b, f32x2 c) {
    asm("v_pk_fma_f32 %0, %1, %2, %0" : "+v"(c) : "v"(a), "v"(b));
    return c;
}

// ---------------- K1: z = x @ W_mix^T (R15 v7 — proven ~55us) ---------------
// Thread (mg owns 4 m-rows, ks owns 32-float k-slice, rr row-half); x staged
// coalesced global->reg->LDS per 32-row tile; each ds_read_b128 feeds 128
// MACs; rotated chunk order spreads banks; red16 DPP reduce; ks==0 stores.
__global__ __launch_bounds__(256) void k_mix(const float* __restrict__ x,
                                             const float* __restrict__ Wmix,
                                             float* __restrict__ z) {
    __shared__ __align__(16) float sx[TROWS * SROW];   // 66 KB
    const int tid = threadIdx.x;
    const int mg = (tid >> 4) & 7, ks = tid & 15, rr = tid >> 7;

    f32x2 w[4][16];
    #pragma unroll
    for (int mm = 0; mm < 4; ++mm) {
        #pragma unroll
        for (int i = 0; i < 8; ++i) {
            const int cj = (i + ks) & 7;
            f32x4 v = *(const f32x4*)(Wmix + (size_t)(4 * mg + mm) * IDIM + ks * 32 + cj * 4);
            w[mm][2*i] = v.xy; w[mm][2*i+1] = v.zw;
        }
    }

    const size_t rowbase = (size_t)blockIdx.x * 256;
    const float* xb = x + rowbase * IDIM;

    f32x4 st[16];
    #pragma unroll
    for (int i = 0; i < 16; ++i)
        st[i] = *(const f32x4*)(xb + (size_t)(tid + 256 * i) * 4);

    for (int t = 0; t < 8; ++t) {
        #pragma unroll
        for (int i = 0; i < 16; ++i) {
            const int v = tid + 256 * i, r = v >> 7, c = v & 127;
            *(f32x4*)(&sx[r * SROW + c * 4]) = st[i];
        }
        __syncthreads();

        if (t + 1 < 8) {
            const float* xn = xb + (size_t)(t + 1) * TROWS * IDIM;
            #pragma unroll
            for (int i = 0; i < 16; ++i)
                st[i] = *(const f32x4*)(xn + (size_t)(tid + 256 * i) * 4);
        }

        float* zp = z + (rowbase + (size_t)t * TROWS) * MIXD + 4 * mg;
        for (int rl = 0; rl < 16; ++rl) {
            const int r = rr * 16 + rl;
            const float* rp = sx + r * SROW + ks * 32;
            f32x2 a0 = {0.f,0.f}, a1 = {0.f,0.f}, a2 = {0.f,0.f}, a3 = {0.f,0.f};
            #pragma unroll
            for (int i = 0; i < 8; ++i) {
                f32x4 v = *(const f32x4*)(rp + ((i + ks) & 7) * 4);
                a0 = pkfma(w[0][2*i], v.xy, a0); a0 = pkfma(w[0][2*i+1], v.zw, a0);
                a1 = pkfma(w[1][2*i], v.xy, a1); a1 = pkfma(w[1][2*i+1], v.zw, a1);
                a2 = pkfma(w[2][2*i], v.xy, a2); a2 = pkfma(w[2][2*i+1], v.zw, a2);
                a3 = pkfma(w[3][2*i], v.xy, a3); a3 = pkfma(w[3][2*i+1], v.zw, a3);
            }
            float s0 = red16(a0.x + a0.y);
            float s1 = red16(a1.x + a1.y);
            float s2 = red16(a2.x + a2.y);
            float s3 = red16(a3.x + a3.y);
            if (ks == 0) {
                f32x4 o4 = { s0, s1, s2, s3 };
                *(f32x4*)(zp + (size_t)r * MIXD) = o4;
            }
        }
        __syncthreads();
    }
}

// ---------------- K2: GRU scan + head (EXACT R12 body — best measured) ------
// 256 threads = 4 waves. Octet (o = tid&7) serves j0, j0+32, j0+64 with an
// 8-way k-split; DPP octet reduce; h[j] owner-resident (hown); exp2 with
// log2e folded into the weights; one barrier per step; zero global ops in
// the loop. Tested-and-rejected variants: z-hoist (R14 +19us), chain-split
// (R14), pk-asm (R15 +13us), ih-precompute (R16 +19us), 2-b/block (R13),
// 12-wave (R8 ~equal), producer-fusion (R10/11 spills).
__global__ __launch_bounds__(256, 1) void k_scan(const float* __restrict__ z,
                                                 const float* __restrict__ Wih,
                                                 const float* __restrict__ Whh,
                                                 const float* __restrict__ bih,
                                                 const float* __restrict__ bhh,
                                                 const float* __restrict__ Whead,
                                                 const float* __restrict__ bhead,
                                                 const float* __restrict__ Wmix,
                                                 float* __restrict__ y) {
    const int b   = blockIdx.x;
    const int tid = threadIdx.x;
    const int j0  = tid >> 3;     // 0..31
    const int o   = tid & 7;      // 0..7
    const float L  = 1.4426950408889634f;   // log2(e)
    const float L2 = 2.8853900817779268f;   // 2*log2(e)

    __shared__ __align__(16) float sz[256 * MIXD];   // 32 KB: half of the z row
    __shared__ __align__(16) float shp[2][HID];      // h ping-pong
    __shared__ __align__(16) float szn[MIXD];

    f32x2 whr[3][6], whu[3][6], whn[3][6], wir[3][2], wiu[3][2], win[3][2];
    float br[3], bu[3], bxn[3], bhn[3];
    #pragma unroll
    for (int i = 0; i < 3; ++i) {
        const int j = j0 + 32 * i;
        #pragma unroll
        for (int c = 0; c < 3; ++c) {
            f32x4 v = *(const f32x4*)(Whh + (size_t)(j        ) * HID + o * 12 + c * 4);
            v *= L;  whr[i][2*c] = v.xy; whr[i][2*c+1] = v.zw;
        }
        #pragma unroll
        for (int c = 0; c < 3; ++c) {
            f32x4 v = *(const f32x4*)(Whh + (size_t)(j +   HID) * HID + o * 12 + c * 4);
            v *= L;  whu[i][2*c] = v.xy; whu[i][2*c+1] = v.zw;
        }
        #pragma unroll
        for (int c = 0; c < 3; ++c) {
            f32x4 v = *(const f32x4*)(Whh + (size_t)(j + 2*HID) * HID + o * 12 + c * 4);
            v *= L2; whn[i][2*c] = v.xy; whn[i][2*c+1] = v.zw;
        }
        {
            f32x4 v = *(const f32x4*)(Wih + (size_t)(j        ) * MIXD + o * 4);
            v *= L;  wir[i][0] = v.xy; wir[i][1] = v.zw;
        }
        {
            f32x4 v = *(const f32x4*)(Wih + (size_t)(j +   HID) * MIXD + o * 4);
            v *= L;  wiu[i][0] = v.xy; wiu[i][1] = v.zw;
        }
        {
            f32x4 v = *(const f32x4*)(Wih + (size_t)(j + 2*HID) * MIXD + o * 4);
            v *= L2; win[i][0] = v.xy; win[i][1] = v.zw;
        }
        br[i]  = (o == 0) ? L  * (bih[j]       + bhh[j])       : 0.f;
        bu[i]  = (o == 0) ? L  * (bih[j + HID] + bhh[j + HID]) : 0.f;
        bxn[i] = (o == 0) ? L2 * bih[j + 2*HID] : 0.f;
        bhn[i] = (o == 0) ? L2 * bhh[j + 2*HID] : 0.f;
    }

    float hown[3] = {0.f, 0.f, 0.f};
    if (tid < HID) shp[0][tid] = 0.f;

    const f32x4* zb4 = (const f32x4*)(z + (size_t)b * TT * MIXD);
    f32x4* sz4 = (f32x4*)sz;

    for (int c = 0; c < TT / 256; ++c) {
        #pragma unroll
        for (int i = 0; i < 8; ++i)
            sz4[tid + 256 * i] = zb4[c * 2048 + tid + 256 * i];
        __syncthreads();

        for (int tt = 0; tt < 256; ++tt) {
            const int t = (c << 8) + tt;
            const float* hr = shp[t & 1];
            float*       hw = shp[(t + 1) & 1];

            const f32x4 z4 = *(const f32x4*)(sz + tt * MIXD + o * 4);
            const f32x4 h0 = *(const f32x4*)(hr + o * 12);
            const f32x4 h1 = *(const f32x4*)(hr + o * 12 + 4);
            const f32x4 h2 = *(const f32x4*)(hr + o * 12 + 8);
            const f32x2 hh[6] = { h0.xy, h0.zw, h1.xy, h1.zw, h2.xy, h2.zw };

            float hv[3];
            #pragma unroll
            for (int i = 0; i < 3; ++i) {
                f32x2 aR  = {br[i],  0.f}, aU  = {bu[i],  0.f};
                f32x2 aXN = {bxn[i], 0.f}, aHN = {bhn[i], 0.f};

                aR  = __builtin_elementwise_fma(wir[i][0], z4.xy, aR);
                aR  = __builtin_elementwise_fma(wir[i][1], z4.zw, aR);
                aU  = __builtin_elementwise_fma(wiu[i][0], z4.xy, aU);
                aU  = __builtin_elementwise_fma(wiu[i][1], z4.zw, aU);
                aXN = __builtin_elementwise_fma(win[i][0], z4.xy, aXN);
                aXN = __builtin_elementwise_fma(win[i][1], z4.zw, aXN);

                #pragma unroll
                for (int k = 0; k < 6; ++k) {
                    aR  = __builtin_elementwise_fma(whr[i][k], hh[k], aR);
                    aU  = __builtin_elementwise_fma(whu[i][k], hh[k], aU);
                    aHN = __builtin_elementwise_fma(whn[i][k], hh[k], aHN);
                }

                float sR  = octet_reduce_lane0(aR.x  + aR.y);
                float sU  = octet_reduce_lane0(aU.x  + aU.y);
                float sXN = octet_reduce_lane0(aXN.x + aXN.y);
                float sHN = octet_reduce_lane0(aHN.x + aHN.y);

                float r = __builtin_amdgcn_rcpf(1.f + EXP2(-sR));
                float u = __builtin_amdgcn_rcpf(1.f + EXP2(-sU));
                float n = 1.f - 2.f * __builtin_amdgcn_rcpf(1.f + EXP2(sXN + r * sHN));
                hv[i] = u * (hown[i] - n) + n;   // lane0 correct; others garbage
                hown[i] = hv[i];
            }
            if (o == 0) {
                hw[j0]      = hv[0];
                hw[j0 + 32] = hv[1];
                hw[j0 + 64] = hv[2];
            }
            __syncthreads();                    // the ONLY barrier per step
        }
    }

    // ---- fused head: zn = Whead @ h + bhead ; y = zn @ Wmix ----
    if (tid < MIXD) {
        const float* h = shp[0];                 // TT even -> final h in shp[0]
        float a0 = 0.f, a1 = 0.f, a2 = 0.f, a3 = 0.f;
        #pragma unroll
        for (int kc = 0; kc < HID / 4; ++kc) {
            f32x4 wv = *(const f32x4*)(Whead + (size_t)tid * HID + kc * 4);
            f32x4 hv4 = *(const f32x4*)(h + kc * 4);
            a0 += wv.x * hv4.x; a1 += wv.y * hv4.y;
            a2 += wv.z * hv4.z; a3 += wv.w * hv4.w;
        }
        szn[tid] = bhead[tid] + ((a0 + a1) + (a2 + a3));
    }
    __syncthreads();
    #pragma unroll
    for (int rep = 0; rep < 2; ++rep) {
        const int col = tid + 256 * rep;
        float acc = 0.f;
        #pragma unroll
        for (int m = 0; m < MIXD; ++m)
            acc += szn[m] * Wmix[(size_t)m * IDIM + col];
        y[(size_t)b * IDIM + col] = acc;
    }
}

extern "C" void kernel_launch(void* const* d_in, const int* in_sizes, int n_in,
                              void* d_out, int out_size, void* d_ws, size_t ws_size,
                              hipStream_t stream) {
    const float* x     = (const float*)d_in[0];
    const float* Wmix  = (const float*)d_in[1];
    const float* Wih   = (const float*)d_in[2];
    const float* Whh   = (const float*)d_in[3];
    const float* bih   = (const float*)d_in[4];
    const float* bhh   = (const float*)d_in[5];
    const float* Whead = (const float*)d_in[6];
    const float* bhead = (const float*)d_in[7];
    float* out = (float*)d_out;

    float* z = (float*)d_ws;   // [B*T, 32] = 16.78 MB

    k_mix <<<512, 256, 0, stream>>>(x, Wmix, z);
    k_scan<<<BB,  256, 0, stream>>>(z, Wih, Whh, bih, bhh, Whead, bhead, Wmix, out);
}